// Round 1
// 339.290 us; speedup vs baseline: 1.0866x; 1.0866x over previous
//
#include <hip/hip_runtime.h>
#include <hip/hip_bf16.h>

// Featurizer: protein graph features + fused linear + layernorm.
// Round-3 changes vs round-2 (368.7us, k_edge 184.5us):
//  * k_edge: coords staged in LDS once per block (was 6x redundant global gathers),
//    rsqrt-based sqrt/normalize, K staging split into 2 passes (32+11 ksteps) over a
//    32KB buffer -> LDS 45.5KB->38.8KB -> 4 blocks/CU (launch_bounds(256,4)).
//  * k_node/k_frames: acos/sin/cos eliminated via sin(s*acos(c))=s*sqrt(1-c^2),
//    cos=c (1 if s==0); logf->__logf; normalize via rsqrt.

#define N_RES   30000
#define N_ATOMS 6
#define LFLAT   (N_RES * N_ATOMS)   // 180000
#define N_EDGES 300000
#define HID     128
#define NODE_IN 44
#define EDGE_IN 688
#define KSTEPS  43                   // 688 / 16
#define KS_A    32                   // ksteps in pass A (RBF pairs 0..31)
#define EPSF    1e-6f
#define LN_EPS  1e-5f
#define MTILE   32                   // edges per block (MFMA M)

typedef unsigned short ushort_t;
typedef short short8 __attribute__((ext_vector_type(8)));
typedef float float16v __attribute__((ext_vector_type(16)));

static __device__ __forceinline__ unsigned short f2bf(float x) {
    __hip_bfloat16 h = __float2bfloat16(x);
    unsigned short u;
    __builtin_memcpy(&u, &h, 2);
    return u;
}

struct F3 { float x, y, z; };
static __device__ __forceinline__ F3 ld3(const float* p, long idx) {   // idx in vec3 units
    F3 r; r.x = p[idx*3+0]; r.y = p[idx*3+1]; r.z = p[idx*3+2]; return r;
}
static __device__ __forceinline__ F3 subv(F3 a, F3 b) { return {a.x-b.x, a.y-b.y, a.z-b.z}; }
static __device__ __forceinline__ float dotv(F3 a, F3 b) { return a.x*b.x + a.y*b.y + a.z*b.z; }
static __device__ __forceinline__ F3 crossv(F3 a, F3 b) {
    return {a.y*b.z - a.z*b.y, a.z*b.x - a.x*b.z, a.x*b.y - a.y*b.x};
}
// 1/max(sqrt(d2),1e-12) == rsqrt(max(d2,1e-24)) (monotone); v_rsq is 1 instr vs ~14.
static __device__ __forceinline__ F3 nrmv(F3 a) {
    float inv = rsqrtf(fmaxf(dotv(a, a), 1e-24f));
    return {a.x*inv, a.y*inv, a.z*inv};
}
static __device__ __forceinline__ float sgn(float x) { return (x > 0.f) ? 1.f : ((x < 0.f) ? -1.f : 0.f); }

// ---------------- kernel: pack edge_W fp32 -> bf16 B-fragment order ----------------
// Wpack[s][w][lane][jj] : B[k][n] with n = w*32 + (lane&31), k = 16s + (lane>>5)*8 + jj,
// where k is the PERMUTED feature index: k<684 -> orig k+4 (rbf/direct), k>=684 -> orig k-684 (quat).
__global__ void k_packw(const float* __restrict__ W, unsigned short* __restrict__ Wp) {
    int s = blockIdx.x;            // 0..42
    int tid = threadIdx.x;         // 0..255
    int w = tid >> 6, lane = tid & 63;
    int ch = w * 32 + (lane & 31);
    int kh = lane >> 5;
    uint4 out;
    uint u[4];
    #pragma unroll
    for (int jp = 0; jp < 4; ++jp) {
        unsigned int lohi[2];
        #pragma unroll
        for (int b = 0; b < 2; ++b) {
            int jj = 2 * jp + b;
            int kn = 16 * s + kh * 8 + jj;
            int ko = (kn < 684) ? (kn + 4) : (kn - 684);
            lohi[b] = f2bf(W[(long)ko * HID + ch]);
        }
        u[jp] = lohi[0] | (lohi[1] << 16);
    }
    out.x = u[0]; out.y = u[1]; out.z = u[2]; out.w = u[3];
    *(uint4*)(Wp + ((size_t)(s * 4 + w) * 64 + lane) * 8) = out;
}

// ---------------- kernel: per-residue frames Q + validity ----------------
__global__ void k_frames(const float* __restrict__ central, const int* __restrict__ batch,
                         float* __restrict__ Qbuf, int* __restrict__ qval) {
    int r = blockIdx.x * 256 + threadIdx.x;
    if (r >= N_RES) return;
    bool bnd   = (r > 0)         && (batch[r]   != batch[r-1]);
    bool bndn  = (r < N_RES - 1) && (batch[r+1] != batch[r]);
    bool valid = (r > 0) && (r < N_RES - 1) && !bnd && !bndn;
    float Q[9] = {0,0,0,0,0,0,0,0,0};
    if (valid) {
        F3 cp = ld3(central, (long)r-1), cc = ld3(central, (long)r), cn = ld3(central, (long)r+1);
        F3 u0 = nrmv(subv(cc, cp));
        F3 u1 = nrmv(subv(cn, cc));
        F3 b  = nrmv(subv(u0, u1));
        F3 n  = nrmv(crossv(u0, u1));
        F3 c  = crossv(b, n);
        Q[0]=b.x; Q[1]=n.x; Q[2]=c.x;     // Q[i*3+j]: i=spatial, j in {b,n,c}
        Q[3]=b.y; Q[4]=n.y; Q[5]=c.y;
        Q[6]=b.z; Q[7]=n.z; Q[8]=c.z;
    }
    #pragma unroll
    for (int k = 0; k < 9; k++) Qbuf[(size_t)r*9 + k] = Q[k];
    qval[r] = valid ? 1 : 0;
}

// ---------------- kernel: node features + 44x128 matmul + LN ----------------
__global__ __launch_bounds__(HID) void k_node(
    const float* __restrict__ coords, const float* __restrict__ central,
    const float* __restrict__ node_W, const float* __restrict__ node_b,
    const float* __restrict__ lnw, const float* __restrict__ lnb,
    const int* __restrict__ batch, const float* __restrict__ Qbuf,
    float* __restrict__ out) {
    int r = blockIdx.x;
    int tid = threadIdx.x;
    __shared__ float feat[NODE_IN];
    __shared__ float red[4];

    if (tid < 6) {
        int c = tid;
        long j = (long)r * N_ATOMS + c;
        bool bnd  = (r > 0)         && (batch[r]   != batch[r-1]);
        bool bndn = (r < N_RES - 1) && (batch[r+1] != batch[r]);
        float sd = 0.f, cd = 0.f;
        bool dm = (j > 0) && (j < LFLAT - 2) && !(bnd && c == 0) && !(bndn && c >= N_ATOMS - 2);
        if (dm) {
            F3 x0 = ld3(coords, j-1), x1 = ld3(coords, j), x2 = ld3(coords, j+1), x3 = ld3(coords, j+2);
            F3 u1 = nrmv(subv(x1, x0)), u2 = nrmv(subv(x2, x1)), u3 = nrmv(subv(x3, x2));
            F3 c1 = nrmv(crossv(u1, u2)), c2 = nrmv(crossv(u2, u3));
            float cc = fminf(fmaxf(dotv(c1, c2), -1.f + EPSF), 1.f - EPSF);
            float s  = sgn(dotv(c2, u1));
            // D = acos(cc)*s;  sin(D) = s*sqrt(1-cc^2); cos(D) = cc (or 1 when s==0 -> D=0)
            sd = s * sqrtf(fmaxf(1.f - cc*cc, 0.f));
            cd = (s != 0.f) ? cc : 1.f;
        }
        feat[2*c] = sd; feat[2*c+1] = cd;
        float sa = 0.f, ca = 0.f;
        bool am = (j > 0) && (j < LFLAT - 1) && !(bnd && c == 0) && !(bndn && c == N_ATOMS - 1);
        if (am) {
            F3 x0 = ld3(coords, j-1), x1 = ld3(coords, j), x2 = ld3(coords, j+1);
            F3 d0 = nrmv(subv(x0, x1)), d1 = nrmv(subv(x2, x1));
            float cv = dotv(d0, d1);
            float t = 1.f - cv*cv + EPSF;        // > 0
            sa = t * rsqrtf(t);                  // sqrt(t)
            ca = cv;
        }
        feat[12 + 2*c] = sa; feat[12 + 2*c + 1] = ca;
    } else if (tid < 11) {
        int a = tid - 6;
        int atom = (a == 0) ? 0 : (a + 1);   // keep atoms {0,2,3,4,5}
        F3 x  = ld3(coords, (long)r * N_ATOMS + atom);
        F3 cx = ld3(central, (long)r);
        F3 d  = subv(x, cx);
        float d2 = dotv(d, d);
        feat[24 + a] = 0.5f * __logf(d2 + EPSF);   // log(sqrt(d2+eps))
        float inv = rsqrtf(fmaxf(d2, 1e-24f));
        float nx = d.x*inv, ny = d.y*inv, nz = d.z*inv;
        const float* Q = Qbuf + (size_t)r * 9;
        #pragma unroll
        for (int i = 0; i < 3; i++)
            feat[29 + a*3 + i] = Q[0+i]*nx + Q[3+i]*ny + Q[6+i]*nz;   // Q^T nhat
    }
    __syncthreads();

    float acc = node_b[tid];
    #pragma unroll
    for (int i = 0; i < NODE_IN; i++)
        acc += feat[i] * node_W[(long)i * HID + tid];

    float s = acc;
    #pragma unroll
    for (int m = 1; m < 64; m <<= 1) s += __shfl_xor(s, m, 64);
    int wv = tid >> 6;
    if ((tid & 63) == 0) red[wv] = s;
    __syncthreads();
    float mu = (red[0] + red[1]) * (1.f / HID);
    float dv = acc - mu;
    float q = dv * dv;
    #pragma unroll
    for (int m = 1; m < 64; m <<= 1) q += __shfl_xor(q, m, 64);
    if ((tid & 63) == 0) red[2 + wv] = q;
    __syncthreads();
    float var = (red[2] + red[3]) * (1.f / HID);
    float y = dv * rsqrtf(var + LN_EPS) * lnw[tid] + lnb[tid];
    out[(size_t)r * HID + tid] = y;
}

// ---------------- kernel: edge features + MFMA 688x128 matmul + LN ----------------
// Block: 256 threads (4 waves), MTILE=32 edges. Wave w computes channels [32w,32w+32).
// K staged in TWO passes over one 32KB buffer:
//   pass A: ksteps 0..31  = RBF pairs 0..31
//   pass B: ksteps 32..42 = RBF pairs 32..35 (local 0..3) + directions (local 4..10) + quat
// Directions for pairs 0..31 computed in pass A, carried in 12 regs (static idx).
// LDS total = 32768 + 4608(cS) + 1152(qtS) + 256(s/t) = 38784 B -> 4 blocks/CU.
__global__ __launch_bounds__(256, 4) void k_edge(
    const float* __restrict__ coords, const int* __restrict__ eidx,
    const unsigned short* __restrict__ Wpack, const float* __restrict__ edge_b,
    const float* __restrict__ lnw, const float* __restrict__ lnb,
    const float* __restrict__ Qbuf, const int* __restrict__ qval,
    float* __restrict__ outE) {
    __shared__ __align__(16) unsigned char smemA[KS_A * 64 * 8 * 2];  // 32768B; reused as C_s[32][132] fp32
    __shared__ float cS[64][18];       // staged coords: slot<32 -> src res of edge slot, else tgt
    __shared__ float qtS[MTILE][9];
    __shared__ int sS[MTILE], tS[MTILE];

    unsigned short* Ast = (unsigned short*)smemA;
    int tid = threadIdx.x;
    int lane = tid & 63;
    int w = tid >> 6;
    int e0 = blockIdx.x * MTILE;

    if (tid < MTILE) {
        sS[tid] = eidx[e0 + tid];
        tS[tid] = eidx[N_EDGES + e0 + tid];
    }
    __syncthreads();

    // ---- stage coords of the 64 touched residues (6 atoms x 3 floats each)
    #pragma unroll
    for (int it = 0; it < 5; ++it) {
        int idx = tid + it * 256;
        if (idx < 64 * 18) {
            int slot = idx / 18;
            int rem  = idx - slot * 18;
            int res  = (slot < 32) ? sS[slot] : tS[slot - 32];
            cS[slot][rem] = coords[(size_t)res * 18 + rem];
        }
    }

    // ---- per-edge quaternion -> regs (written to LDS in pass B: local kstep 10)
    uint2 qpk;
    if (tid < MTILE) {
        int s = sS[tid];
        int t = tS[tid];
        float Qs[9], Qt[9];
        #pragma unroll
        for (int k = 0; k < 9; k++) {
            Qs[k] = Qbuf[(size_t)s*9 + k];
            Qt[k] = Qbuf[(size_t)t*9 + k];
            qtS[tid][k] = Qt[k];
        }
        float R[9];   // R[i][j] = sum_k Qt[k][i] * Qs[k][j]
        #pragma unroll
        for (int i = 0; i < 3; i++)
            #pragma unroll
            for (int jj = 0; jj < 3; jj++)
                R[i*3+jj] = Qt[0+i]*Qs[0+jj] + Qt[3+i]*Qs[3+jj] + Qt[6+i]*Qs[6+jj];
        float m0 = 0.5f * sqrtf(fabsf(1.f + R[0] - R[4] - R[8]));
        float m1 = 0.5f * sqrtf(fabsf(1.f - R[0] + R[4] - R[8]));
        float m2 = 0.5f * sqrtf(fabsf(1.f - R[0] - R[4] + R[8]));
        float xq = sgn(R[7] - R[5]) * m0;
        float yq = sgn(R[2] - R[6]) * m1;
        float zq = sgn(R[3] - R[1]) * m2;
        float wq = 0.5f * sqrtf(fmaxf(1.f + R[0] + R[4] + R[8], 0.f));
        float nq2 = xq*xq + yq*yq + zq*zq + wq*wq;
        float inv = rsqrtf(fmaxf(nq2, 1e-24f));
        float vm = (qval[s] && qval[t]) ? 1.f : 0.f;
        qpk.x = f2bf(xq * inv * vm) | ((unsigned int)f2bf(yq * inv * vm) << 16);
        qpk.y = f2bf(zq * inv * vm) | ((unsigned int)f2bf(wq * inv * vm) << 16);
    }
    __syncthreads();   // cS + qtS ready

    int e  = tid & 31;
    int p0 = tid >> 5;   // 0..7

    // ---- pass A features: RBF for pairs 0..31 into ksteps 0..31; dirs saved in regs
    float vdir[4][3];
    #pragma unroll
    for (int it = 0; it < 4; ++it) {
        int pair = p0 + 8 * it;          // 0..31
        int ta = pair / 6, sa = pair - ta * 6;
        float dx = cS[e][sa*3+0] - cS[32+e][ta*3+0];
        float dy = cS[e][sa*3+1] - cS[32+e][ta*3+1];
        float dz = cS[e][sa*3+2] - cS[32+e][ta*3+2];
        float d2 = dx*dx + dy*dy + dz*dz;
        float t  = d2 + EPSF;
        float D  = t * rsqrtf(t);        // sqrt(d2+eps), t > 0
        float a8 = D * 0.8f;             // (D - mu_i)*0.8 = a8 - i*1.0666667
        unsigned int u[8];
        #pragma unroll
        for (int i = 0; i < 8; i++) {
            float z0 = a8 - (float)(2*i)     * 1.06666672f;
            float z1 = a8 - (float)(2*i + 1) * 1.06666672f;
            u[i] = f2bf(__expf(-(z0*z0))) | ((unsigned int)f2bf(__expf(-(z1*z1))) << 16);
        }
        uint4 lo; lo.x = u[0]; lo.y = u[1]; lo.z = u[2]; lo.w = u[3];
        uint4 hi; hi.x = u[4]; hi.y = u[5]; hi.z = u[6]; hi.w = u[7];
        *(uint4*)(Ast + (pair * 64 + e) * 8)      = lo;
        *(uint4*)(Ast + (pair * 64 + 32 + e) * 8) = hi;
        float inv = rsqrtf(fmaxf(d2, 1e-24f));
        float nx = dx*inv, ny = dy*inv, nz = dz*inv;
        #pragma unroll
        for (int i = 0; i < 3; i++)
            vdir[it][i] = qtS[e][0+i]*nx + qtS[e][3+i]*ny + qtS[e][6+i]*nz;
    }
    __syncthreads();

    // ---- MFMA pass A: ksteps 0..31
    float16v acc;
    #pragma unroll
    for (int i = 0; i < 16; i++) acc[i] = 0.f;
    const short8* Ap = (const short8*)smemA;
    const short8* Bp = (const short8*)Wpack;
    for (int s = 0; s < KS_A; ++s) {
        short8 a = Ap[s * 64 + lane];
        short8 b = Bp[(s * 4 + w) * 64 + lane];
        acc = __builtin_amdgcn_mfma_f32_32x32x16_bf16(a, b, acc, 0, 0, 0);
    }
    __syncthreads();   // everyone done reading pass-A staging

    // ---- pass B features into local ksteps 0..10 (global 32..42)
    if (tid < 128) {                      // RBF pairs 32..35 + their directions
        int e2 = tid & 31;
        int pair = 32 + (tid >> 5);
        int ta = pair / 6, sa = pair - ta * 6;
        float dx = cS[e2][sa*3+0] - cS[32+e2][ta*3+0];
        float dy = cS[e2][sa*3+1] - cS[32+e2][ta*3+1];
        float dz = cS[e2][sa*3+2] - cS[32+e2][ta*3+2];
        float d2 = dx*dx + dy*dy + dz*dz;
        float t  = d2 + EPSF;
        float D  = t * rsqrtf(t);
        float a8 = D * 0.8f;
        unsigned int u[8];
        #pragma unroll
        for (int i = 0; i < 8; i++) {
            float z0 = a8 - (float)(2*i)     * 1.06666672f;
            float z1 = a8 - (float)(2*i + 1) * 1.06666672f;
            u[i] = f2bf(__expf(-(z0*z0))) | ((unsigned int)f2bf(__expf(-(z1*z1))) << 16);
        }
        uint4 lo; lo.x = u[0]; lo.y = u[1]; lo.z = u[2]; lo.w = u[3];
        uint4 hi; hi.x = u[4]; hi.y = u[5]; hi.z = u[6]; hi.w = u[7];
        int lks = pair - 32;              // local kstep 0..3
        *(uint4*)(Ast + (lks * 64 + e2) * 8)      = lo;
        *(uint4*)(Ast + (lks * 64 + 32 + e2) * 8) = hi;
        float inv = rsqrtf(fmaxf(d2, 1e-24f));
        float nx = dx*inv, ny = dy*inv, nz = dz*inv;
        #pragma unroll
        for (int i = 0; i < 3; i++) {
            float v = qtS[e2][0+i]*nx + qtS[e2][3+i]*ny + qtS[e2][6+i]*nz;
            int kn = 576 + pair * 3 + i;
            int s2 = kn >> 4, r2 = kn & 15;
            Ast[(((s2 - 32) * 64) + (r2 >> 3) * 32 + e2) * 8 + (r2 & 7)] = f2bf(v);
        }
    }
    #pragma unroll
    for (int it = 0; it < 4; ++it) {      // saved directions, pairs 0..31
        int pair = p0 + 8 * it;
        #pragma unroll
        for (int i = 0; i < 3; i++) {
            int kn = 576 + pair * 3 + i;
            int s2 = kn >> 4, r2 = kn & 15;
            Ast[(((s2 - 32) * 64) + (r2 >> 3) * 32 + e) * 8 + (r2 & 7)] = f2bf(vdir[it][i]);
        }
    }
    if (tid < MTILE)                      // quat: global kstep 42 -> local 10, rows 32.., jj 4..7
        *(uint2*)(Ast + ((10 * 64 + 32 + tid) * 8 + 4)) = qpk;
    __syncthreads();

    // ---- MFMA pass B: ksteps 32..42 (accumulate into same acc)
    for (int s = KS_A; s < KSTEPS; ++s) {
        short8 a = Ap[(s - KS_A) * 64 + lane];
        short8 b = Bp[(s * 4 + w) * 64 + lane];
        acc = __builtin_amdgcn_mfma_f32_32x32x16_bf16(a, b, acc, 0, 0, 0);
    }

    // ---- epilogue: acc -> C_s (reuse staging buffer), then bias + LN + store
    __syncthreads();
    float* C_s = (float*)smemA;   // [32][132] = 16896B, fits in 32768
    int col = lane & 31;
    #pragma unroll
    for (int r = 0; r < 16; ++r) {
        int row = (r & 3) + 8 * (r >> 2) + 4 * (lane >> 5);   // verified C/D layout (m74/m101)
        C_s[row * 132 + w * 32 + col] = acc[r];
    }
    __syncthreads();

    int ee = tid >> 3;          // 0..31
    int p  = tid & 7;           // 16-channel slice
    const float* Crow = C_s + ee * 132 + p * 16;
    float x[16];
    float sum = 0.f;
    #pragma unroll
    for (int j = 0; j < 16; ++j) {
        x[j] = Crow[j] + edge_b[p * 16 + j];
        sum += x[j];
    }
    #pragma unroll
    for (int m = 1; m < 8; m <<= 1) sum += __shfl_xor(sum, m, 64);
    float mu = sum * (1.f / HID);
    float vs = 0.f;
    #pragma unroll
    for (int j = 0; j < 16; ++j) { float d = x[j] - mu; vs += d * d; }
    #pragma unroll
    for (int m = 1; m < 8; m <<= 1) vs += __shfl_xor(vs, m, 64);
    float is = rsqrtf(vs * (1.f / HID) + LN_EPS);
    float* op = outE + (size_t)(e0 + ee) * HID + p * 16;
    #pragma unroll
    for (int j = 0; j < 16; ++j) {
        int ch = p * 16 + j;
        op[j] = (x[j] - mu) * is * lnw[ch] + lnb[ch];
    }
}

extern "C" void kernel_launch(void* const* d_in, const int* in_sizes, int n_in,
                              void* d_out, int out_size, void* d_ws, size_t ws_size,
                              hipStream_t stream) {
    (void)in_sizes; (void)n_in; (void)out_size; (void)ws_size;
    const float* coords  = (const float*)d_in[0];
    const float* central = (const float*)d_in[1];
    const float* node_W  = (const float*)d_in[2];
    const float* node_b  = (const float*)d_in[3];
    const float* node_lw = (const float*)d_in[4];
    const float* node_lb = (const float*)d_in[5];
    const float* edge_W  = (const float*)d_in[6];
    const float* edge_b  = (const float*)d_in[7];
    const float* edge_lw = (const float*)d_in[8];
    const float* edge_lb = (const float*)d_in[9];
    const int*   batch   = (const int*)d_in[10];
    const int*   eidx    = (const int*)d_in[11];

    // ws: [Wpack bf16: 88064 el = 176128 B][Qbuf: 270000 f][qval: 30000 i] ~= 1.38 MB
    unsigned short* Wpack = (unsigned short*)d_ws;
    float* Qbuf = (float*)((char*)d_ws + (size_t)EDGE_IN * HID * 2);
    int*   qval = (int*)(Qbuf + (size_t)N_RES * 9);

    float* outV = (float*)d_out;
    float* outE = outV + (size_t)N_RES * HID;

    hipLaunchKernelGGL(k_packw,  dim3(KSTEPS),            dim3(256), 0, stream, edge_W, Wpack);
    hipLaunchKernelGGL(k_frames, dim3((N_RES + 255)/256), dim3(256), 0, stream, central, batch, Qbuf, qval);
    hipLaunchKernelGGL(k_node,   dim3(N_RES),             dim3(HID), 0, stream,
                       coords, central, node_W, node_b, node_lw, node_lb, batch, Qbuf, outV);
    hipLaunchKernelGGL(k_edge,   dim3(N_EDGES / MTILE),   dim3(256), 0, stream,
                       coords, eidx, Wpack, edge_b, edge_lw, edge_lb, Qbuf, qval, outE);
}